// Round 1
// baseline (2053.960 us; speedup 1.0000x reference)
//
#include <hip/hip_runtime.h>
#include <stdint.h>
#include <math.h>

#define B_ 2
#define S_ 2048
#define H_ 4096
#define NH_ 32
#define HD_ 128

using s16x8 = __attribute__((ext_vector_type(8))) short;
using f32x4 = __attribute__((ext_vector_type(4))) float;

__device__ __forceinline__ unsigned short f2b(float f) {
  union { float f; unsigned u; } v; v.f = f;
  unsigned r = v.u + 0x7FFFu + ((v.u >> 16) & 1u);
  return (unsigned short)(r >> 16);
}
__device__ __forceinline__ float b2f(unsigned short h) {
  union { unsigned u; float f; } v; v.u = ((unsigned)h) << 16;
  return v.f;
}

__device__ __forceinline__ void async_cp16(const void* g, void* l) {
  __builtin_amdgcn_global_load_lds(
      (__attribute__((address_space(1))) void*)(void*)g,
      (__attribute__((address_space(3))) void*)l, 16, 0, 0);
}

// ---------------- cast fp32 -> bf16 ----------------
__global__ void cast_f32_bf16(const float* __restrict__ in,
                              unsigned short* __restrict__ out, long n) {
  long i = ((long)blockIdx.x * 256 + threadIdx.x) * 4;
  if (i >= n) return;
  const float4 v = *(const float4*)(in + i);
  ushort4 o;
  o.x = f2b(v.x); o.y = f2b(v.y); o.z = f2b(v.z); o.w = f2b(v.w);
  *(ushort4*)(out + i) = o;
}

// ------- transpose+cast: in (4096 x in_stride fp32, use 4096 cols) -> out 4096x4096 bf16 (transposed) -------
__global__ void transpose_cast_4096(const float* __restrict__ in,
                                    unsigned short* __restrict__ out, int in_stride) {
  __shared__ float tile[64][65];
  const int c0 = blockIdx.x * 64;
  const int r0 = blockIdx.y * 64;
  const int tx = threadIdx.x & 63, ty = threadIdx.x >> 6;
#pragma unroll
  for (int i = 0; i < 64; i += 4)
    tile[ty + i][tx] = in[(long)(r0 + ty + i) * in_stride + c0 + tx];
  __syncthreads();
#pragma unroll
  for (int i = 0; i < 64; i += 4)
    out[(long)(c0 + ty + i) * 4096 + r0 + tx] = f2b(tile[tx][ty + i]);
}

// ---------------- GEMM: C(MxN) = A(MxK) * Bt(NxK)^T, bf16 in, fp32 acc ----------------
// MODE 0: write fp32 C.  MODE 1: write bf16 into (B,NH,S,HD) layout (N must be 4096).
template <int MODE>
__global__ __launch_bounds__(256, 2) void gemm_bt(
    const unsigned short* __restrict__ A,
    const unsigned short* __restrict__ Bt,
    float* __restrict__ Cf,
    unsigned short* __restrict__ Dst,
    int M, int N, int K) {
  __shared__ __align__(16) unsigned short As[4096];  // [kchunk 0..3][row 0..127] x 8 bf16
  __shared__ __align__(16) unsigned short Bs[4096];
  const int tid = threadIdx.x;
  const int w = tid >> 6, lane = tid & 63;
  const int quad = lane >> 4, l16 = lane & 15;
  const int wm = w >> 1, wn = w & 1;
  const int m0 = blockIdx.y * 128, n0 = blockIdx.x * 128;

  const f32x4 z4 = {0.f, 0.f, 0.f, 0.f};
  f32x4 acc[4][4];
#pragma unroll
  for (int i = 0; i < 4; i++)
#pragma unroll
    for (int j = 0; j < 4; j++) acc[i][j] = z4;

  const int s0 = tid, s1 = tid + 256;
  const unsigned short* ga0 = A + (long)(m0 + (s0 & 127)) * K + (s0 >> 7) * 8;
  const unsigned short* ga1 = A + (long)(m0 + (s1 & 127)) * K + (s1 >> 7) * 8;
  const unsigned short* gb0 = Bt + (long)(n0 + (s0 & 127)) * K + (s0 >> 7) * 8;
  const unsigned short* gb1 = Bt + (long)(n0 + (s1 & 127)) * K + (s1 >> 7) * 8;
  unsigned short* la0 = &As[s0 * 8];
  unsigned short* la1 = &As[s1 * 8];
  unsigned short* lb0 = &Bs[s0 * 8];
  unsigned short* lb1 = &Bs[s1 * 8];

  for (int k0 = 0; k0 < K; k0 += 32) {
    __syncthreads();
    async_cp16(ga0 + k0, la0);
    async_cp16(ga1 + k0, la1);
    async_cp16(gb0 + k0, lb0);
    async_cp16(gb1 + k0, lb1);
    __syncthreads();
    s16x8 af[4], bfr[4];
#pragma unroll
    for (int mi = 0; mi < 4; mi++)
      af[mi] = *(const s16x8*)&As[(quad * 128 + wm * 64 + mi * 16 + l16) * 8];
#pragma unroll
    for (int ni = 0; ni < 4; ni++)
      bfr[ni] = *(const s16x8*)&Bs[(quad * 128 + wn * 64 + ni * 16 + l16) * 8];
#pragma unroll
    for (int mi = 0; mi < 4; mi++)
#pragma unroll
      for (int ni = 0; ni < 4; ni++)
        acc[mi][ni] = __builtin_amdgcn_mfma_f32_16x16x32_bf16(af[mi], bfr[ni], acc[mi][ni], 0, 0, 0);
  }

#pragma unroll
  for (int mi = 0; mi < 4; mi++)
#pragma unroll
    for (int ni = 0; ni < 4; ni++) {
      const int row = m0 + wm * 64 + mi * 16 + quad * 4;
      const int col = n0 + wn * 64 + ni * 16 + l16;
      if (MODE == 0) {
#pragma unroll
        for (int r = 0; r < 4; r++)
          Cf[(long)(row + r) * N + col] = acc[mi][ni][r];
      } else {
        const int h = col >> 7, d = col & 127;
#pragma unroll
        for (int r = 0; r < 4; r++) {
          const int m = row + r;
          const int b = m >> 11, s = m & 2047;
          Dst[((long)((b * NH_ + h) * S_) + s) * HD_ + d] = f2b(acc[mi][ni][r]);
        }
      }
    }
}

// ---------------- RoPE (NeoX) in-place on Q and K, layout (B,NH,S,HD) bf16 ----------------
__global__ void rope_kernel(unsigned short* __restrict__ Qb,
                            unsigned short* __restrict__ Kb,
                            const int* __restrict__ pos_ids) {
  const long idx = (long)blockIdx.x * 256 + threadIdx.x;  // B*NH*S*64
  const int i = (int)(idx & 63);
  const long row = idx >> 6;  // (b*NH+h)*S + s
  const int s = (int)(row & (S_ - 1));
  const long bh = row >> 11;
  const int b = (int)(bh >> 5);
  const float pos = (float)pos_ids[b * S_ + s];
  // inv_freq = 10000^(-i/64) = 2^(-i*log2(10000)/64)
  const float inv = exp2f(-(float)i * 0.20762050593046f);
  const float ang = pos * inv;
  const float sn = sinf(ang), cs = cosf(ang);
  const long base = row * HD_;
  const float q1 = b2f(Qb[base + i]), q2 = b2f(Qb[base + 64 + i]);
  Qb[base + i] = f2b(q1 * cs - q2 * sn);
  Qb[base + 64 + i] = f2b(q2 * cs + q1 * sn);
  const float k1 = b2f(Kb[base + i]), k2 = b2f(Kb[base + 64 + i]);
  Kb[base + i] = f2b(k1 * cs - k2 * sn);
  Kb[base + 64 + i] = f2b(k2 * cs + k1 * sn);
}

// ---------------- per-head transpose V (S x HD) -> Vt (HD x S), bf16 ----------------
__global__ void transpose_v(const unsigned short* __restrict__ V,
                            unsigned short* __restrict__ Vt) {
  __shared__ unsigned short tile[64][66];
  const int bh = blockIdx.z;
  const int s0 = blockIdx.x * 64;
  const int d0 = blockIdx.y * 64;
  const unsigned short* src = V + (long)bh * S_ * HD_;
  unsigned short* dst = Vt + (long)bh * S_ * HD_;
  const int tx = threadIdx.x & 63, ty = threadIdx.x >> 6;
#pragma unroll
  for (int i = 0; i < 64; i += 4)
    tile[ty + i][tx] = src[(long)(s0 + ty + i) * HD_ + d0 + tx];
  __syncthreads();
#pragma unroll
  for (int i = 0; i < 64; i += 4)
    dst[(long)(d0 + ty + i) * S_ + s0 + tx] = tile[tx][ty + i];
}

// ---------------- flash attention (causal), bf16 in, fp32 softmax/acc ----------------
// grid (qtile 0..15, bh 0..63), 256 threads = 4 waves; wave w owns q-rows [q0+32w, q0+32w+32)
__global__ __launch_bounds__(256, 2) void flash_attn(
    const unsigned short* __restrict__ Qb,   // (B,NH,S,HD)
    const unsigned short* __restrict__ Kb,   // (B,NH,S,HD)
    const unsigned short* __restrict__ Vt,   // (B,NH,HD,S)
    unsigned short* __restrict__ Ab) {       // (B,S,H) bf16
  __shared__ __align__(16) unsigned short plds[128 * 136];  // P, row stride 136
  const int tid = threadIdx.x;
  const int w = tid >> 6, lane = tid & 63;
  const int quad = lane >> 4, l16 = lane & 15;
  const int qt = blockIdx.x;
  const int bh = blockIdx.y;
  const int b = bh >> 5, h = bh & 31;
  const int q0 = qt * 128;
  const int wq = q0 + w * 32;

  const unsigned short* Qh = Qb + (long)bh * S_ * HD_;
  const unsigned short* Kh = Kb + (long)bh * S_ * HD_;
  const unsigned short* Vh = Vt + (long)bh * S_ * HD_;

  s16x8 qf[2][4];
#pragma unroll
  for (int rb = 0; rb < 2; rb++)
#pragma unroll
    for (int ks = 0; ks < 4; ks++)
      qf[rb][ks] = *(const s16x8*)(Qh + (long)(wq + rb * 16 + l16) * HD_ + ks * 32 + quad * 8);

  const f32x4 z4 = {0.f, 0.f, 0.f, 0.f};
  f32x4 oacc[2][8];
#pragma unroll
  for (int rb = 0; rb < 2; rb++)
#pragma unroll
    for (int oc = 0; oc < 8; oc++) oacc[rb][oc] = z4;
  float mrow[2][4], lrow[2][4];
#pragma unroll
  for (int rb = 0; rb < 2; rb++)
#pragma unroll
    for (int r = 0; r < 4; r++) { mrow[rb][r] = -3.0e38f; lrow[rb][r] = 0.f; }

  const float scale = 0.08838834764831845f;  // 1/sqrt(128)

  for (int kt = 0; kt <= qt; kt++) {
    const int kbase = kt * 128;
    f32x4 sacc[2][8];
#pragma unroll
    for (int rb = 0; rb < 2; rb++)
#pragma unroll
      for (int ni = 0; ni < 8; ni++) sacc[rb][ni] = z4;

#pragma unroll
    for (int ni = 0; ni < 8; ni++) {
#pragma unroll
      for (int ks = 0; ks < 4; ks++) {
        const s16x8 kf = *(const s16x8*)(Kh + (long)(kbase + ni * 16 + l16) * HD_ + ks * 32 + quad * 8);
        sacc[0][ni] = __builtin_amdgcn_mfma_f32_16x16x32_bf16(qf[0][ks], kf, sacc[0][ni], 0, 0, 0);
        sacc[1][ni] = __builtin_amdgcn_mfma_f32_16x16x32_bf16(qf[1][ks], kf, sacc[1][ni], 0, 0, 0);
      }
    }

    const bool diag = (kt == qt);
#pragma unroll
    for (int rb = 0; rb < 2; rb++) {
      const int rloc = w * 32 + rb * 16 + quad * 4;  // local q row of reg 0
      // scale + causal mask
#pragma unroll
      for (int ni = 0; ni < 8; ni++)
#pragma unroll
        for (int r = 0; r < 4; r++) {
          float v = sacc[rb][ni][r] * scale;
          if (diag && (ni * 16 + l16 > rloc + r)) v = -3.0e38f;
          sacc[rb][ni][r] = v;
        }
      float mn[4], alpha[4];
#pragma unroll
      for (int r = 0; r < 4; r++) {
        float m = sacc[rb][0][r];
#pragma unroll
        for (int ni = 1; ni < 8; ni++) m = fmaxf(m, sacc[rb][ni][r]);
#pragma unroll
        for (int off = 1; off < 16; off <<= 1) m = fmaxf(m, __shfl_xor(m, off));
        mn[r] = fmaxf(mrow[rb][r], m);
        alpha[r] = __expf(mrow[rb][r] - mn[r]);
        mrow[rb][r] = mn[r];
      }
      float rs[4] = {0.f, 0.f, 0.f, 0.f};
#pragma unroll
      for (int ni = 0; ni < 8; ni++)
#pragma unroll
        for (int r = 0; r < 4; r++) {
          const float p = __expf(sacc[rb][ni][r] - mn[r]);
          rs[r] += p;
          plds[(rloc + r) * 136 + ni * 16 + l16] = f2b(p);
        }
#pragma unroll
      for (int r = 0; r < 4; r++) {
        float t = rs[r];
#pragma unroll
        for (int off = 1; off < 16; off <<= 1) t += __shfl_xor(t, off);
        lrow[rb][r] = lrow[rb][r] * alpha[r] + t;
      }
#pragma unroll
      for (int oc = 0; oc < 8; oc++)
#pragma unroll
        for (int r = 0; r < 4; r++) oacc[rb][oc][r] *= alpha[r];
    }

    // P (A-layout) from LDS: wave reads only rows it wrote -> no barrier needed
    s16x8 af[2][4];
#pragma unroll
    for (int rb = 0; rb < 2; rb++)
#pragma unroll
      for (int ks = 0; ks < 4; ks++)
        af[rb][ks] = *(const s16x8*)&plds[(w * 32 + rb * 16 + l16) * 136 + ks * 32 + quad * 8];
#pragma unroll
    for (int oc = 0; oc < 8; oc++) {
#pragma unroll
      for (int ks = 0; ks < 4; ks++) {
        const s16x8 vf = *(const s16x8*)(Vh + (long)(oc * 16 + l16) * S_ + kbase + ks * 32 + quad * 8);
        oacc[0][oc] = __builtin_amdgcn_mfma_f32_16x16x32_bf16(af[0][ks], vf, oacc[0][oc], 0, 0, 0);
        oacc[1][oc] = __builtin_amdgcn_mfma_f32_16x16x32_bf16(af[1][ks], vf, oacc[1][oc], 0, 0, 0);
      }
    }
  }

#pragma unroll
  for (int rb = 0; rb < 2; rb++) {
    float inv_l[4];
#pragma unroll
    for (int r = 0; r < 4; r++) inv_l[r] = 1.f / lrow[rb][r];
#pragma unroll
    for (int oc = 0; oc < 8; oc++)
#pragma unroll
      for (int r = 0; r < 4; r++) {
        const int s = q0 + w * 32 + rb * 16 + quad * 4 + r;
        const int d = oc * 16 + l16;
        Ab[((long)(b * S_ + s)) * H_ + h * HD_ + d] = f2b(oacc[rb][oc][r] * inv_l[r]);
      }
  }
}

extern "C" void kernel_launch(void* const* d_in, const int* in_sizes, int n_in,
                              void* d_out, int out_size, void* d_ws, size_t ws_size,
                              hipStream_t stream) {
  const float* hs = (const float*)d_in[0];
  const float* w_qkv = (const float*)d_in[1];
  const float* w_o = (const float*)d_in[2];
  const int* pos = (const int*)d_in[3];
  float* out = (float*)d_out;

  const long EL = (long)4096 * 4096;  // 16.78M elems
  unsigned short* Xb = (unsigned short*)d_ws;   // also reused as Ab after QKV GEMMs
  unsigned short* Wt = Xb + EL;
  unsigned short* Qb = Wt + EL;
  unsigned short* Kb = Qb + EL;
  unsigned short* Vb = Kb + EL;
  unsigned short* Vt = Vb + EL;
  unsigned short* Ab = Xb;  // alias: Xb dead after third QKV GEMM
  // total ws: 6*EL*2 = 192 MiB

  cast_f32_bf16<<<(EL / 4 + 255) / 256, 256, 0, stream>>>(hs, Xb, EL);

  unsigned short* qkv_dst[3] = {Qb, Kb, Vb};
  for (int p = 0; p < 3; p++) {
    transpose_cast_4096<<<dim3(64, 64), 256, 0, stream>>>(w_qkv + p * 4096, Wt, 12288);
    gemm_bt<1><<<dim3(32, 32), 256, 0, stream>>>(Xb, Wt, nullptr, qkv_dst[p], 4096, 4096, 4096);
  }

  rope_kernel<<<(B_ * NH_ * S_ * 64) / 256, 256, 0, stream>>>(Qb, Kb, pos);
  transpose_v<<<dim3(32, 2, 64), 256, 0, stream>>>(Vb, Vt);
  flash_attn<<<dim3(16, 64), 256, 0, stream>>>(Qb, Kb, Vt, Ab);

  transpose_cast_4096<<<dim3(64, 64), 256, 0, stream>>>(w_o, Wt, 4096);
  gemm_bt<0><<<dim3(32, 32), 256, 0, stream>>>(Ab, Wt, out, nullptr, 4096, 4096, 4096);
}

// Round 2
// 1794.415 us; speedup vs baseline: 1.1446x; 1.1446x over previous
//
#include <hip/hip_runtime.h>
#include <stdint.h>
#include <math.h>

#define B_ 2
#define S_ 2048
#define H_ 4096
#define NH_ 32
#define HD_ 128

using s16x8 = __attribute__((ext_vector_type(8))) short;
using f32x4 = __attribute__((ext_vector_type(4))) float;

__device__ __forceinline__ unsigned short f2b(float f) {
  union { float f; unsigned u; } v; v.f = f;
  unsigned r = v.u + 0x7FFFu + ((v.u >> 16) & 1u);
  return (unsigned short)(r >> 16);
}
__device__ __forceinline__ float b2f(unsigned short h) {
  union { unsigned u; float f; } v; v.u = ((unsigned)h) << 16;
  return v.f;
}

__device__ __forceinline__ void async_cp16(const void* g, void* l) {
  __builtin_amdgcn_global_load_lds(
      (__attribute__((address_space(1))) void*)(void*)g,
      (__attribute__((address_space(3))) void*)l, 16, 0, 0);
}

// ---------------- cast fp32 -> bf16 ----------------
__global__ void cast_f32_bf16(const float* __restrict__ in,
                              unsigned short* __restrict__ out, long n) {
  long i = ((long)blockIdx.x * 256 + threadIdx.x) * 4;
  if (i >= n) return;
  const float4 v = *(const float4*)(in + i);
  ushort4 o;
  o.x = f2b(v.x); o.y = f2b(v.y); o.z = f2b(v.z); o.w = f2b(v.w);
  *(ushort4*)(out + i) = o;
}

// ------- transpose+cast: in (4096 x in_stride fp32, use 4096 cols) -> out 4096x4096 bf16 (transposed) -------
__global__ void transpose_cast_4096(const float* __restrict__ in,
                                    unsigned short* __restrict__ out, int in_stride) {
  __shared__ float tile[64][65];
  const int c0 = blockIdx.x * 64;
  const int r0 = blockIdx.y * 64;
  const int tx = threadIdx.x & 63, ty = threadIdx.x >> 6;
#pragma unroll
  for (int i = 0; i < 64; i += 4)
    tile[ty + i][tx] = in[(long)(r0 + ty + i) * in_stride + c0 + tx];
  __syncthreads();
#pragma unroll
  for (int i = 0; i < 64; i += 4)
    out[(long)(c0 + ty + i) * 4096 + r0 + tx] = f2b(tile[tx][ty + i]);
}

// ---------------- GEMM: C(MxN) = A(MxK) * Bt(NxK)^T, bf16 in, fp32 acc ----------------
template <int MODE>
__global__ __launch_bounds__(256, 2) void gemm_bt(
    const unsigned short* __restrict__ A,
    const unsigned short* __restrict__ Bt,
    float* __restrict__ Cf,
    unsigned short* __restrict__ Dst,
    int M, int N, int K) {
  __shared__ __align__(16) unsigned short As[4096];
  __shared__ __align__(16) unsigned short Bs[4096];
  const int tid = threadIdx.x;
  const int w = tid >> 6, lane = tid & 63;
  const int quad = lane >> 4, l16 = lane & 15;
  const int wm = w >> 1, wn = w & 1;
  const int m0 = blockIdx.y * 128, n0 = blockIdx.x * 128;

  const f32x4 z4 = {0.f, 0.f, 0.f, 0.f};
  f32x4 acc[4][4];
#pragma unroll
  for (int i = 0; i < 4; i++)
#pragma unroll
    for (int j = 0; j < 4; j++) acc[i][j] = z4;

  const int s0 = tid, s1 = tid + 256;
  const unsigned short* ga0 = A + (long)(m0 + (s0 & 127)) * K + (s0 >> 7) * 8;
  const unsigned short* ga1 = A + (long)(m0 + (s1 & 127)) * K + (s1 >> 7) * 8;
  const unsigned short* gb0 = Bt + (long)(n0 + (s0 & 127)) * K + (s0 >> 7) * 8;
  const unsigned short* gb1 = Bt + (long)(n0 + (s1 & 127)) * K + (s1 >> 7) * 8;
  unsigned short* la0 = &As[s0 * 8];
  unsigned short* la1 = &As[s1 * 8];
  unsigned short* lb0 = &Bs[s0 * 8];
  unsigned short* lb1 = &Bs[s1 * 8];

  for (int k0 = 0; k0 < K; k0 += 32) {
    __syncthreads();
    async_cp16(ga0 + k0, la0);
    async_cp16(ga1 + k0, la1);
    async_cp16(gb0 + k0, lb0);
    async_cp16(gb1 + k0, lb1);
    __syncthreads();
    s16x8 af[4], bfr[4];
#pragma unroll
    for (int mi = 0; mi < 4; mi++)
      af[mi] = *(const s16x8*)&As[(quad * 128 + wm * 64 + mi * 16 + l16) * 8];
#pragma unroll
    for (int ni = 0; ni < 4; ni++)
      bfr[ni] = *(const s16x8*)&Bs[(quad * 128 + wn * 64 + ni * 16 + l16) * 8];
#pragma unroll
    for (int mi = 0; mi < 4; mi++)
#pragma unroll
      for (int ni = 0; ni < 4; ni++)
        acc[mi][ni] = __builtin_amdgcn_mfma_f32_16x16x32_bf16(af[mi], bfr[ni], acc[mi][ni], 0, 0, 0);
  }

#pragma unroll
  for (int mi = 0; mi < 4; mi++)
#pragma unroll
    for (int ni = 0; ni < 4; ni++) {
      const int row = m0 + wm * 64 + mi * 16 + quad * 4;
      const int col = n0 + wn * 64 + ni * 16 + l16;
      if (MODE == 0) {
#pragma unroll
        for (int r = 0; r < 4; r++)
          Cf[(long)(row + r) * N + col] = acc[mi][ni][r];
      } else {
        const int h = col >> 7, d = col & 127;
#pragma unroll
        for (int r = 0; r < 4; r++) {
          const int m = row + r;
          const int b = m >> 11, s = m & 2047;
          Dst[((long)((b * NH_ + h) * S_) + s) * HD_ + d] = f2b(acc[mi][ni][r]);
        }
      }
    }
}

// ---------------- RoPE (NeoX) in-place on Q and K ----------------
__global__ void rope_kernel(unsigned short* __restrict__ Qb,
                            unsigned short* __restrict__ Kb,
                            const int* __restrict__ pos_ids) {
  const long idx = (long)blockIdx.x * 256 + threadIdx.x;
  const int i = (int)(idx & 63);
  const long row = idx >> 6;
  const int s = (int)(row & (S_ - 1));
  const long bh = row >> 11;
  const int b = (int)(bh >> 5);
  const float pos = (float)pos_ids[b * S_ + s];
  const float inv = exp2f(-(float)i * 0.20762050593046f);
  const float ang = pos * inv;
  const float sn = sinf(ang), cs = cosf(ang);
  const long base = row * HD_;
  const float q1 = b2f(Qb[base + i]), q2 = b2f(Qb[base + 64 + i]);
  Qb[base + i] = f2b(q1 * cs - q2 * sn);
  Qb[base + 64 + i] = f2b(q2 * cs + q1 * sn);
  const float k1 = b2f(Kb[base + i]), k2 = b2f(Kb[base + 64 + i]);
  Kb[base + i] = f2b(k1 * cs - k2 * sn);
  Kb[base + 64 + i] = f2b(k2 * cs + k1 * sn);
}

// ---------------- per-head transpose V (S x HD) -> Vt (HD x S) ----------------
__global__ void transpose_v(const unsigned short* __restrict__ V,
                            unsigned short* __restrict__ Vt) {
  __shared__ unsigned short tile[64][66];
  const int bh = blockIdx.z;
  const int s0 = blockIdx.x * 64;
  const int d0 = blockIdx.y * 64;
  const unsigned short* src = V + (long)bh * S_ * HD_;
  unsigned short* dst = Vt + (long)bh * S_ * HD_;
  const int tx = threadIdx.x & 63, ty = threadIdx.x >> 6;
#pragma unroll
  for (int i = 0; i < 64; i += 4)
    tile[ty + i][tx] = src[(long)(s0 + ty + i) * HD_ + d0 + tx];
  __syncthreads();
#pragma unroll
  for (int i = 0; i < 64; i += 4)
    dst[(long)(d0 + ty + i) * S_ + s0 + tx] = tile[tx][ty + i];
}

// ---------------- flash attention (causal), LDS-staged K/V ----------------
// grid (qtile 0..15, bh 0..63), 256 threads = 4 waves; wave w owns q-rows [q0+32w, q0+32w+32)
// k-tile = 64. K staged as [dchunk 0..15][krow 0..63]x8, V as [kchunk 0..7][drow 0..127]x8.
__global__ __launch_bounds__(256, 2) void flash_attn(
    const unsigned short* __restrict__ Qb,   // (B,NH,S,HD)
    const unsigned short* __restrict__ Kb,   // (B,NH,S,HD)
    const unsigned short* __restrict__ Vt,   // (B,NH,HD,S)
    unsigned short* __restrict__ Ab) {       // (B,S,H) bf16
  __shared__ __align__(16) unsigned short Ks[16 * 64 * 8];   // 16 KB
  __shared__ __align__(16) unsigned short Vs[8 * 128 * 8];   // 16 KB
  __shared__ __align__(16) unsigned short plds[128 * 72];    // 18 KB, row stride 72
  const int tid = threadIdx.x;
  const int w = tid >> 6, lane = tid & 63;
  const int quad = lane >> 4, l16 = lane & 15;
  const int qt = blockIdx.x;
  const int bh = blockIdx.y;
  const int b = bh >> 5, h = bh & 31;
  const int q0 = qt * 128;
  const int wq = q0 + w * 32;

  const unsigned short* Qh = Qb + (long)bh * S_ * HD_;
  const unsigned short* Kh = Kb + (long)bh * S_ * HD_;
  const unsigned short* Vh = Vt + (long)bh * S_ * HD_;

  // staging source pointers (per-thread, advance by kbase each tile)
  const unsigned short* kstage = Kh + (long)(tid & 63) * HD_ + (tid >> 6) * 8;
  const unsigned short* vstage = Vh + (long)(tid & 127) * S_ + (tid >> 7) * 8;

  s16x8 qf[2][4];
#pragma unroll
  for (int rb = 0; rb < 2; rb++)
#pragma unroll
    for (int ks = 0; ks < 4; ks++)
      qf[rb][ks] = *(const s16x8*)(Qh + (long)(wq + rb * 16 + l16) * HD_ + ks * 32 + quad * 8);

  const f32x4 z4 = {0.f, 0.f, 0.f, 0.f};
  f32x4 oacc[2][8];
#pragma unroll
  for (int rb = 0; rb < 2; rb++)
#pragma unroll
    for (int oc = 0; oc < 8; oc++) oacc[rb][oc] = z4;
  float mrow[2][4], lrow[2][4];
#pragma unroll
  for (int rb = 0; rb < 2; rb++)
#pragma unroll
    for (int r = 0; r < 4; r++) { mrow[rb][r] = -3.0e38f; lrow[rb][r] = 0.f; }

  const float scale = 0.08838834764831845f;  // 1/sqrt(128)
  const int nkt = 2 * qt + 2;

  for (int kt = 0; kt < nkt; kt++) {
    const int kbase = kt * 64;
    __syncthreads();  // previous tile's LDS reads done before overwrite
#pragma unroll
    for (int j = 0; j < 4; j++)
      async_cp16(kstage + (long)kbase * HD_ + j * 32, &Ks[(j * 256 + tid) * 8]);
#pragma unroll
    for (int j = 0; j < 4; j++)
      async_cp16(vstage + kbase + j * 16, &Vs[(j * 256 + tid) * 8]);
    __syncthreads();  // vmcnt drained before barrier -> staged data visible

    // ---- QK^T: 128 q x 64 k ----
    f32x4 sacc[2][4];
#pragma unroll
    for (int rb = 0; rb < 2; rb++)
#pragma unroll
      for (int ni = 0; ni < 4; ni++) sacc[rb][ni] = z4;
#pragma unroll
    for (int ni = 0; ni < 4; ni++) {
#pragma unroll
      for (int ks = 0; ks < 4; ks++) {
        const s16x8 kf = *(const s16x8*)&Ks[((ks * 4 + quad) * 64 + ni * 16 + l16) * 8];
        sacc[0][ni] = __builtin_amdgcn_mfma_f32_16x16x32_bf16(qf[0][ks], kf, sacc[0][ni], 0, 0, 0);
        sacc[1][ni] = __builtin_amdgcn_mfma_f32_16x16x32_bf16(qf[1][ks], kf, sacc[1][ni], 0, 0, 0);
      }
    }

    const bool band = (kbase + 64 > q0 + w * 32);  // wave-uniform: tile touches diagonal
#pragma unroll
    for (int rb = 0; rb < 2; rb++) {
      const int rloc = w * 32 + rb * 16 + quad * 4;
#pragma unroll
      for (int ni = 0; ni < 4; ni++)
#pragma unroll
        for (int r = 0; r < 4; r++) {
          float v = sacc[rb][ni][r] * scale;
          if (band && (kbase + ni * 16 + l16 > q0 + rloc + r)) v = -3.0e38f;
          sacc[rb][ni][r] = v;
        }
      float mn[4], alpha[4];
#pragma unroll
      for (int r = 0; r < 4; r++) {
        float m = sacc[rb][0][r];
#pragma unroll
        for (int ni = 1; ni < 4; ni++) m = fmaxf(m, sacc[rb][ni][r]);
#pragma unroll
        for (int off = 1; off < 16; off <<= 1) m = fmaxf(m, __shfl_xor(m, off));
        mn[r] = fmaxf(mrow[rb][r], m);
        alpha[r] = __expf(mrow[rb][r] - mn[r]);
        mrow[rb][r] = mn[r];
      }
      float rs[4] = {0.f, 0.f, 0.f, 0.f};
#pragma unroll
      for (int ni = 0; ni < 4; ni++)
#pragma unroll
        for (int r = 0; r < 4; r++) {
          const float p = __expf(sacc[rb][ni][r] - mn[r]);
          rs[r] += p;
          plds[(rloc + r) * 72 + ni * 16 + l16] = f2b(p);
        }
#pragma unroll
      for (int r = 0; r < 4; r++) {
        float t = rs[r];
#pragma unroll
        for (int off = 1; off < 16; off <<= 1) t += __shfl_xor(t, off);
        lrow[rb][r] = lrow[rb][r] * alpha[r] + t;
      }
#pragma unroll
      for (int oc = 0; oc < 8; oc++)
#pragma unroll
        for (int r = 0; r < 4; r++) oacc[rb][oc][r] *= alpha[r];
    }

    // P (A-layout) from LDS: wave reads only rows it wrote -> no barrier needed
    s16x8 af[2][2];
#pragma unroll
    for (int rb = 0; rb < 2; rb++)
#pragma unroll
      for (int ks = 0; ks < 2; ks++)
        af[rb][ks] = *(const s16x8*)&plds[(w * 32 + rb * 16 + l16) * 72 + ks * 32 + quad * 8];
#pragma unroll
    for (int oc = 0; oc < 8; oc++) {
#pragma unroll
      for (int ks = 0; ks < 2; ks++) {
        const s16x8 vf = *(const s16x8*)&Vs[((ks * 4 + quad) * 128 + oc * 16 + l16) * 8];
        oacc[0][oc] = __builtin_amdgcn_mfma_f32_16x16x32_bf16(af[0][ks], vf, oacc[0][oc], 0, 0, 0);
        oacc[1][oc] = __builtin_amdgcn_mfma_f32_16x16x32_bf16(af[1][ks], vf, oacc[1][oc], 0, 0, 0);
      }
    }
  }

#pragma unroll
  for (int rb = 0; rb < 2; rb++) {
    float inv_l[4];
#pragma unroll
    for (int r = 0; r < 4; r++) inv_l[r] = 1.f / lrow[rb][r];
#pragma unroll
    for (int oc = 0; oc < 8; oc++)
#pragma unroll
      for (int r = 0; r < 4; r++) {
        const int s = q0 + w * 32 + rb * 16 + quad * 4 + r;
        const int d = oc * 16 + l16;
        Ab[((long)(b * S_ + s)) * H_ + h * HD_ + d] = f2b(oacc[rb][oc][r] * inv_l[r]);
      }
  }
}

extern "C" void kernel_launch(void* const* d_in, const int* in_sizes, int n_in,
                              void* d_out, int out_size, void* d_ws, size_t ws_size,
                              hipStream_t stream) {
  const float* hs = (const float*)d_in[0];
  const float* w_qkv = (const float*)d_in[1];
  const float* w_o = (const float*)d_in[2];
  const int* pos = (const int*)d_in[3];
  float* out = (float*)d_out;

  const long EL = (long)4096 * 4096;
  unsigned short* Xb = (unsigned short*)d_ws;
  unsigned short* Wt = Xb + EL;
  unsigned short* Qb = Wt + EL;
  unsigned short* Kb = Qb + EL;
  unsigned short* Vb = Kb + EL;
  unsigned short* Vt = Vb + EL;
  unsigned short* Ab = Xb;  // alias: Xb dead after third QKV GEMM

  cast_f32_bf16<<<(EL / 4 + 255) / 256, 256, 0, stream>>>(hs, Xb, EL);

  unsigned short* qkv_dst[3] = {Qb, Kb, Vb};
  for (int p = 0; p < 3; p++) {
    transpose_cast_4096<<<dim3(64, 64), 256, 0, stream>>>(w_qkv + p * 4096, Wt, 12288);
    gemm_bt<1><<<dim3(32, 32), 256, 0, stream>>>(Xb, Wt, nullptr, qkv_dst[p], 4096, 4096, 4096);
  }

  rope_kernel<<<(B_ * NH_ * S_ * 64) / 256, 256, 0, stream>>>(Qb, Kb, pos);
  transpose_v<<<dim3(32, 2, 64), 256, 0, stream>>>(Vb, Vt);
  flash_attn<<<dim3(16, 64), 256, 0, stream>>>(Qb, Kb, Vt, Ab);

  transpose_cast_4096<<<dim3(64, 64), 256, 0, stream>>>(w_o, Wt, 4096);
  gemm_bt<0><<<dim3(32, 32), 256, 0, stream>>>(Ab, Wt, out, nullptr, 4096, 4096, 4096);
}

// Round 3
// 1621.045 us; speedup vs baseline: 1.2671x; 1.1069x over previous
//
#include <hip/hip_runtime.h>
#include <stdint.h>
#include <math.h>

#define B_ 2
#define S_ 2048
#define H_ 4096
#define NH_ 32
#define HD_ 128

using s16x8 = __attribute__((ext_vector_type(8))) short;
using f32x4 = __attribute__((ext_vector_type(4))) float;

__device__ __forceinline__ unsigned short f2b(float f) {
  union { float f; unsigned u; } v; v.f = f;
  unsigned r = v.u + 0x7FFFu + ((v.u >> 16) & 1u);
  return (unsigned short)(r >> 16);
}
__device__ __forceinline__ unsigned short f2b_trunc(float f) {
  union { float f; unsigned u; } v; v.f = f;
  return (unsigned short)(v.u >> 16);
}
__device__ __forceinline__ float b2f(unsigned short h) {
  union { unsigned u; float f; } v; v.u = ((unsigned)h) << 16;
  return v.f;
}

__device__ __forceinline__ void async_cp16(const void* g, void* l) {
  __builtin_amdgcn_global_load_lds(
      (__attribute__((address_space(1))) void*)(void*)g,
      (__attribute__((address_space(3))) void*)l, 16, 0, 0);
}

// ---------------- cast fp32 -> bf16 ----------------
__global__ void cast_f32_bf16(const float* __restrict__ in,
                              unsigned short* __restrict__ out, long n) {
  long i = ((long)blockIdx.x * 256 + threadIdx.x) * 4;
  if (i >= n) return;
  const float4 v = *(const float4*)(in + i);
  ushort4 o;
  o.x = f2b(v.x); o.y = f2b(v.y); o.z = f2b(v.z); o.w = f2b(v.w);
  *(ushort4*)(out + i) = o;
}

// ------- transpose+cast: in (4096 x in_stride fp32, use 4096 cols) -> out 4096x4096 bf16 (transposed) -------
__global__ void transpose_cast_4096(const float* __restrict__ in,
                                    unsigned short* __restrict__ out, int in_stride) {
  __shared__ float tile[64][65];
  const int c0 = blockIdx.x * 64;
  const int r0 = blockIdx.y * 64;
  const int tx = threadIdx.x & 63, ty = threadIdx.x >> 6;
#pragma unroll
  for (int i = 0; i < 64; i += 4)
    tile[ty + i][tx] = in[(long)(r0 + ty + i) * in_stride + c0 + tx];
  __syncthreads();
#pragma unroll
  for (int i = 0; i < 64; i += 4)
    out[(long)(c0 + ty + i) * 4096 + r0 + tx] = f2b(tile[tx][ty + i]);
}

// ---------------- GEMM: C(MxN) = A(MxK) * Bt(NxK)^T, bf16 in, fp32 acc ----------------
template <int MODE>
__global__ __launch_bounds__(256, 2) void gemm_bt(
    const unsigned short* __restrict__ A,
    const unsigned short* __restrict__ Bt,
    float* __restrict__ Cf,
    unsigned short* __restrict__ Dst,
    int M, int N, int K) {
  __shared__ __align__(16) unsigned short As[4096];
  __shared__ __align__(16) unsigned short Bs[4096];
  const int tid = threadIdx.x;
  const int w = tid >> 6, lane = tid & 63;
  const int quad = lane >> 4, l16 = lane & 15;
  const int wm = w >> 1, wn = w & 1;
  const int m0 = blockIdx.y * 128, n0 = blockIdx.x * 128;

  const f32x4 z4 = {0.f, 0.f, 0.f, 0.f};
  f32x4 acc[4][4];
#pragma unroll
  for (int i = 0; i < 4; i++)
#pragma unroll
    for (int j = 0; j < 4; j++) acc[i][j] = z4;

  const int s0 = tid, s1 = tid + 256;
  const unsigned short* ga0 = A + (long)(m0 + (s0 & 127)) * K + (s0 >> 7) * 8;
  const unsigned short* ga1 = A + (long)(m0 + (s1 & 127)) * K + (s1 >> 7) * 8;
  const unsigned short* gb0 = Bt + (long)(n0 + (s0 & 127)) * K + (s0 >> 7) * 8;
  const unsigned short* gb1 = Bt + (long)(n0 + (s1 & 127)) * K + (s1 >> 7) * 8;
  unsigned short* la0 = &As[s0 * 8];
  unsigned short* la1 = &As[s1 * 8];
  unsigned short* lb0 = &Bs[s0 * 8];
  unsigned short* lb1 = &Bs[s1 * 8];

  for (int k0 = 0; k0 < K; k0 += 32) {
    __syncthreads();
    async_cp16(ga0 + k0, la0);
    async_cp16(ga1 + k0, la1);
    async_cp16(gb0 + k0, lb0);
    async_cp16(gb1 + k0, lb1);
    __syncthreads();
    s16x8 af[4], bfr[4];
#pragma unroll
    for (int mi = 0; mi < 4; mi++)
      af[mi] = *(const s16x8*)&As[(quad * 128 + wm * 64 + mi * 16 + l16) * 8];
#pragma unroll
    for (int ni = 0; ni < 4; ni++)
      bfr[ni] = *(const s16x8*)&Bs[(quad * 128 + wn * 64 + ni * 16 + l16) * 8];
#pragma unroll
    for (int mi = 0; mi < 4; mi++)
#pragma unroll
      for (int ni = 0; ni < 4; ni++)
        acc[mi][ni] = __builtin_amdgcn_mfma_f32_16x16x32_bf16(af[mi], bfr[ni], acc[mi][ni], 0, 0, 0);
  }

#pragma unroll
  for (int mi = 0; mi < 4; mi++)
#pragma unroll
    for (int ni = 0; ni < 4; ni++) {
      const int row = m0 + wm * 64 + mi * 16 + quad * 4;
      const int col = n0 + wn * 64 + ni * 16 + l16;
      if (MODE == 0) {
#pragma unroll
        for (int r = 0; r < 4; r++)
          Cf[(long)(row + r) * N + col] = acc[mi][ni][r];
      } else {
        const int h = col >> 7, d = col & 127;
#pragma unroll
        for (int r = 0; r < 4; r++) {
          const int m = row + r;
          const int b = m >> 11, s = m & 2047;
          Dst[((long)((b * NH_ + h) * S_) + s) * HD_ + d] = f2b(acc[mi][ni][r]);
        }
      }
    }
}

// ---------------- RoPE (NeoX) in-place on Q and K; Q pre-scaled by 1/sqrt(d)*log2(e) ----------------
__global__ void rope_kernel(unsigned short* __restrict__ Qb,
                            unsigned short* __restrict__ Kb,
                            const int* __restrict__ pos_ids) {
  const float QSCALE = 1.4426950408889634f * 0.08838834764831845f;  // log2(e)/sqrt(128)
  const long idx = (long)blockIdx.x * 256 + threadIdx.x;
  const int i = (int)(idx & 63);
  const long row = idx >> 6;
  const int s = (int)(row & (S_ - 1));
  const long bh = row >> 11;
  const int b = (int)(bh >> 5);
  const float pos = (float)pos_ids[b * S_ + s];
  const float inv = exp2f(-(float)i * 0.20762050593046f);
  const float ang = pos * inv;
  const float sn = sinf(ang), cs = cosf(ang);
  const long base = row * HD_;
  const float q1 = b2f(Qb[base + i]), q2 = b2f(Qb[base + 64 + i]);
  Qb[base + i] = f2b((q1 * cs - q2 * sn) * QSCALE);
  Qb[base + 64 + i] = f2b((q2 * cs + q1 * sn) * QSCALE);
  const float k1 = b2f(Kb[base + i]), k2 = b2f(Kb[base + 64 + i]);
  Kb[base + i] = f2b(k1 * cs - k2 * sn);
  Kb[base + 64 + i] = f2b(k2 * cs + k1 * sn);
}

// ---------------- per-head transpose V (S x HD) -> Vt (HD x S) ----------------
__global__ void transpose_v(const unsigned short* __restrict__ V,
                            unsigned short* __restrict__ Vt) {
  __shared__ unsigned short tile[64][66];
  const int bh = blockIdx.z;
  const int s0 = blockIdx.x * 64;
  const int d0 = blockIdx.y * 64;
  const unsigned short* src = V + (long)bh * S_ * HD_;
  unsigned short* dst = Vt + (long)bh * S_ * HD_;
  const int tx = threadIdx.x & 63, ty = threadIdx.x >> 6;
#pragma unroll
  for (int i = 0; i < 64; i += 4)
    tile[ty + i][tx] = src[(long)(s0 + ty + i) * HD_ + d0 + tx];
  __syncthreads();
#pragma unroll
  for (int i = 0; i < 64; i += 4)
    dst[(long)(d0 + ty + i) * S_ + s0 + tx] = tile[tx][ty + i];
}

// ---------------- flash attention (causal), LDS-staged K/V, balanced pair grid ----------------
// grid (qx 0..7, bh 0..63): block processes q-tiles {15-qx, qx} -> uniform 36 k-tiles/block.
// 256 threads = 4 waves; wave w owns q-rows [q0+32w, q0+32w+32). k-tile = 64.
// Scores arrive pre-scaled to log2 domain (Q carries 1/sqrt(d)*log2e).
__global__ __launch_bounds__(256, 2) void flash_attn(
    const unsigned short* __restrict__ Qb,   // (B,NH,S,HD)
    const unsigned short* __restrict__ Kb,   // (B,NH,S,HD)
    const unsigned short* __restrict__ Vt,   // (B,NH,HD,S)
    unsigned short* __restrict__ Ab) {       // (B,S,H) bf16
  __shared__ __align__(16) unsigned short Ks[16 * 64 * 8];   // 16 KB
  __shared__ __align__(16) unsigned short Vs[8 * 128 * 8];   // 16 KB
  __shared__ __align__(16) unsigned short plds[128 * 72];    // 18 KB
  const int tid = threadIdx.x;
  const int w = tid >> 6, lane = tid & 63;
  const int quad = lane >> 4, l16 = lane & 15;
  const int qx = blockIdx.x;
  const int bh = blockIdx.y;
  const int b = bh >> 5, h = bh & 31;

  const unsigned short* Qh = Qb + (long)bh * S_ * HD_;
  const unsigned short* Kh = Kb + (long)bh * S_ * HD_;
  const unsigned short* Vh = Vt + (long)bh * S_ * HD_;

  const unsigned short* kstage = Kh + (long)(tid & 63) * HD_ + (tid >> 6) * 8;
  const unsigned short* vstage = Vh + (long)(tid & 127) * S_ + (tid >> 7) * 8;

  const f32x4 z4 = {0.f, 0.f, 0.f, 0.f};

  for (int half = 0; half < 2; half++) {
    const int qt = half ? qx : 15 - qx;   // heavy tile first
    const int q0 = qt * 128;
    const int wq = q0 + w * 32;

    s16x8 qf[2][4];
#pragma unroll
    for (int rb = 0; rb < 2; rb++)
#pragma unroll
      for (int ks = 0; ks < 4; ks++)
        qf[rb][ks] = *(const s16x8*)(Qh + (long)(wq + rb * 16 + l16) * HD_ + ks * 32 + quad * 8);

    f32x4 oacc[2][8];
#pragma unroll
    for (int rb = 0; rb < 2; rb++)
#pragma unroll
      for (int oc = 0; oc < 8; oc++) oacc[rb][oc] = z4;
    float mrow[2][4], lrow[2][4];
#pragma unroll
    for (int rb = 0; rb < 2; rb++)
#pragma unroll
      for (int r = 0; r < 4; r++) { mrow[rb][r] = -3.0e38f; lrow[rb][r] = 0.f; }

    const int nkt = 2 * qt + 2;

    for (int kt = 0; kt < nkt; kt++) {
      const int kbase = kt * 64;
      __syncthreads();
#pragma unroll
      for (int j = 0; j < 4; j++)
        async_cp16(kstage + (long)kbase * HD_ + j * 32, &Ks[(j * 256 + tid) * 8]);
#pragma unroll
      for (int j = 0; j < 4; j++)
        async_cp16(vstage + kbase + j * 16, &Vs[(j * 256 + tid) * 8]);
      __syncthreads();

      // ---- QK^T: 128 q x 64 k (log2-domain scores) ----
      f32x4 sacc[2][4];
#pragma unroll
      for (int rb = 0; rb < 2; rb++)
#pragma unroll
        for (int ni = 0; ni < 4; ni++) sacc[rb][ni] = z4;
#pragma unroll
      for (int ni = 0; ni < 4; ni++) {
#pragma unroll
        for (int ks = 0; ks < 4; ks++) {
          const s16x8 kf = *(const s16x8*)&Ks[((ks * 4 + quad) * 64 + ni * 16 + l16) * 8];
          sacc[0][ni] = __builtin_amdgcn_mfma_f32_16x16x32_bf16(qf[0][ks], kf, sacc[0][ni], 0, 0, 0);
          sacc[1][ni] = __builtin_amdgcn_mfma_f32_16x16x32_bf16(qf[1][ks], kf, sacc[1][ni], 0, 0, 0);
        }
      }

      const bool band = (kbase + 64 > q0 + w * 32);  // wave-uniform
#pragma unroll
      for (int rb = 0; rb < 2; rb++) {
        const int rloc = w * 32 + rb * 16 + quad * 4;
        if (band) {
#pragma unroll
          for (int ni = 0; ni < 4; ni++)
#pragma unroll
            for (int r = 0; r < 4; r++)
              if (kbase + ni * 16 + l16 > q0 + rloc + r) sacc[rb][ni][r] = -3.0e38f;
        }
        float mn[4], alpha[4];
#pragma unroll
        for (int r = 0; r < 4; r++) {
          float m = fmaxf(fmaxf(sacc[rb][0][r], sacc[rb][1][r]),
                          fmaxf(sacc[rb][2][r], sacc[rb][3][r]));
#pragma unroll
          for (int off = 1; off < 16; off <<= 1) m = fmaxf(m, __shfl_xor(m, off));
          mn[r] = fmaxf(mrow[rb][r], m);
          alpha[r] = __builtin_amdgcn_exp2f(mrow[rb][r] - mn[r]);
          mrow[rb][r] = mn[r];
        }
        float rs[4] = {0.f, 0.f, 0.f, 0.f};
#pragma unroll
        for (int ni = 0; ni < 4; ni++)
#pragma unroll
          for (int r = 0; r < 4; r++) {
            const float p = __builtin_amdgcn_exp2f(sacc[rb][ni][r] - mn[r]);
            rs[r] += p;
            plds[(rloc + r) * 72 + ni * 16 + l16] = f2b_trunc(p);
          }
#pragma unroll
        for (int r = 0; r < 4; r++) {
          float t = rs[r];
#pragma unroll
          for (int off = 1; off < 16; off <<= 1) t += __shfl_xor(t, off);
          lrow[rb][r] = lrow[rb][r] * alpha[r] + t;
        }
#pragma unroll
        for (int oc = 0; oc < 8; oc++)
#pragma unroll
          for (int r = 0; r < 4; r++) oacc[rb][oc][r] *= alpha[r];
      }

      // P (A-layout) from LDS: wave reads only rows it wrote -> no barrier needed
      s16x8 af[2][2];
#pragma unroll
      for (int rb = 0; rb < 2; rb++)
#pragma unroll
        for (int ks = 0; ks < 2; ks++)
          af[rb][ks] = *(const s16x8*)&plds[(w * 32 + rb * 16 + l16) * 72 + ks * 32 + quad * 8];
#pragma unroll
      for (int oc = 0; oc < 8; oc++) {
#pragma unroll
        for (int ks = 0; ks < 2; ks++) {
          const s16x8 vf = *(const s16x8*)&Vs[((ks * 4 + quad) * 128 + oc * 16 + l16) * 8];
          oacc[0][oc] = __builtin_amdgcn_mfma_f32_16x16x32_bf16(af[0][ks], vf, oacc[0][oc], 0, 0, 0);
          oacc[1][oc] = __builtin_amdgcn_mfma_f32_16x16x32_bf16(af[1][ks], vf, oacc[1][oc], 0, 0, 0);
        }
      }
    }

#pragma unroll
    for (int rb = 0; rb < 2; rb++) {
      float inv_l[4];
#pragma unroll
      for (int r = 0; r < 4; r++) inv_l[r] = 1.f / lrow[rb][r];
#pragma unroll
      for (int oc = 0; oc < 8; oc++)
#pragma unroll
        for (int r = 0; r < 4; r++) {
          const int s = q0 + w * 32 + rb * 16 + quad * 4 + r;
          const int d = oc * 16 + l16;
          Ab[((long)(b * S_ + s)) * H_ + h * HD_ + d] = f2b(oacc[rb][oc][r] * inv_l[r]);
        }
    }
  }
}

extern "C" void kernel_launch(void* const* d_in, const int* in_sizes, int n_in,
                              void* d_out, int out_size, void* d_ws, size_t ws_size,
                              hipStream_t stream) {
  const float* hs = (const float*)d_in[0];
  const float* w_qkv = (const float*)d_in[1];
  const float* w_o = (const float*)d_in[2];
  const int* pos = (const int*)d_in[3];
  float* out = (float*)d_out;

  const long EL = (long)4096 * 4096;
  unsigned short* Xb = (unsigned short*)d_ws;
  unsigned short* Wt = Xb + EL;
  unsigned short* Qb = Wt + EL;
  unsigned short* Kb = Qb + EL;
  unsigned short* Vb = Kb + EL;
  unsigned short* Vt = Vb + EL;
  unsigned short* Ab = Xb;  // alias: Xb dead after third QKV GEMM

  cast_f32_bf16<<<(EL / 4 + 255) / 256, 256, 0, stream>>>(hs, Xb, EL);

  unsigned short* qkv_dst[3] = {Qb, Kb, Vb};
  for (int p = 0; p < 3; p++) {
    transpose_cast_4096<<<dim3(64, 64), 256, 0, stream>>>(w_qkv + p * 4096, Wt, 12288);
    gemm_bt<1><<<dim3(32, 32), 256, 0, stream>>>(Xb, Wt, nullptr, qkv_dst[p], 4096, 4096, 4096);
  }

  rope_kernel<<<(B_ * NH_ * S_ * 64) / 256, 256, 0, stream>>>(Qb, Kb, pos);
  transpose_v<<<dim3(32, 2, 64), 256, 0, stream>>>(Vb, Vt);
  flash_attn<<<dim3(8, 64), 256, 0, stream>>>(Qb, Kb, Vt, Ab);

  transpose_cast_4096<<<dim3(64, 64), 256, 0, stream>>>(w_o, Wt, 4096);
  gemm_bt<0><<<dim3(32, 32), 256, 0, stream>>>(Ab, Wt, out, nullptr, 4096, 4096, 4096);
}